// Round 13
// baseline (43.774 us; speedup 1.0000x reference)
//
#include <hip/hip_runtime.h>

constexpr int PL = 128;

typedef float f32x2 __attribute__((ext_vector_type(2)));

__device__ __forceinline__ float fast_exp2(float x) {
#if __has_builtin(__builtin_amdgcn_exp2f)
    return __builtin_amdgcn_exp2f(x);
#else
    return __expf(x * 0.69314718055994531f);   // e^(x ln2) = 2^x
#endif
}
// exact IEEE f32 fma per lane; builtin codegen beat hand asm in r11 A/B
__device__ __forceinline__ f32x2 pk_fma(f32x2 a, f32x2 b, f32x2 c) {
    return __builtin_elementwise_fma(a, b, c);
}
__device__ __forceinline__ f32x2 sp(float v) { f32x2 r; r.x = v; r.y = v; return r; }

// ---------------- Kernel A: stage j-pair records + per-seq sum(x) into d_ws ----
// record[seq][jp] (12 floats): {x*c0, x*c0', x*s0, x*s0', x*c1, x*c1', x*s1, x*s1',
//                               v, v', v*x, (v*x)'}
__global__ __launch_bounds__(256, 4) void stage_kernel(
    const float* __restrict__ x, const float* __restrict__ t, const int* __restrict__ mask,
    float* __restrict__ tab, float* __restrict__ xsum)
{
    const int tid  = threadIdx.x;
    const int seq  = blockIdx.x * 4 + (tid >> 6);
    const int jp   = tid & 63;
    const int base = seq * PL + jp * 2;
    const float2 xv = *reinterpret_cast<const float2*>(x + base);
    const float2 tv = *reinterpret_cast<const float2*>(t + base);
    const int2   mv = *reinterpret_cast<const int2*>(mask + base);
    const float va0 = mv.x ? 1.f : 0.f;
    const float va1 = mv.y ? 1.f : 0.f;
    const float th1 = 0.031622776601683794f;   // 1000^-0.5
    float4* r4 = reinterpret_cast<float4*>(tab + (size_t)seq * 768 + jp * 12);
    r4[0] = make_float4(xv.x * __cosf(tv.x),       xv.y * __cosf(tv.y),
                        xv.x * __sinf(tv.x),       xv.y * __sinf(tv.y));
    r4[1] = make_float4(xv.x * __cosf(tv.x * th1), xv.y * __cosf(tv.y * th1),
                        xv.x * __sinf(tv.x * th1), xv.y * __sinf(tv.y * th1));
    r4[2] = make_float4(va0, va1, va0 * xv.x, va1 * xv.y);
    float px = xv.x + xv.y;                      // wave = one seq -> full reduce
    #pragma unroll
    for (int off = 32; off >= 1; off >>= 1) px += __shfl_xor(px, off);
    if (jp == 0) xsum[seq] = px;
}

// ---------------- Kernel B: attention + FFN; j-records streamed via scalar pipe ----
__global__ __launch_bounds__(256, 8) void attn_kernel(
    const float* __restrict__ x, const float* __restrict__ t, const int* __restrict__ mask,
    const float* __restrict__ tab, const float* __restrict__ xsum,
    const float* __restrict__ Wq, const float* __restrict__ Wk, const float* __restrict__ Wv,
    const float* __restrict__ Wout, const float* __restrict__ W1, const float* __restrict__ b1,
    const float* __restrict__ W2, const float* __restrict__ b2,
    float* __restrict__ out)
{
    __shared__ f32x2 w1p[32][16];       // [hid-pair][dim]
    __shared__ __align__(8) float cg[64];
    __shared__ __align__(8) float b1s[64];
    __shared__ float OST[4][PL];
    __shared__ float P[2][PL];
    __shared__ __align__(16) float woutS[16];
    __shared__ float bbS;

    const int tid = threadIdx.x;
    const int seq = blockIdx.x;

    // ---- weight staging (no barrier needed until FFN) ----
    #pragma unroll
    for (int k = 0; k < 4; ++k) {
        const int idx = tid + k * 256;
        const int hid = idx >> 4, d = idx & 15;
        reinterpret_cast<float*>(w1p)[((hid >> 1) * 16 + d) * 2 + (hid & 1)] = W1[idx];
    }
    if (tid < 64) {
        b1s[tid] = b1[tid];
        float c = 0.f;
        #pragma unroll
        for (int d = 0; d < 16; ++d) c += W2[d * 64 + tid] * Wout[d];   // W2^T @ wout
        cg[tid] = c;
    }
    if (tid < 16) woutS[tid] = Wout[tid];
    if (tid == 0) {
        float bb = 0.f;
        #pragma unroll
        for (int d = 0; d < 16; ++d) bb += b2[d] * Wout[d];
        bbS = bb;
    }

    // ---- attention: wave = head; lane owns rows rA, rB; j-data via s_load ----
    {
        const int h  = tid >> 6;            // wave-uniform head
        const int rA = tid & 63, rB = rA + 64;
        const float4 wq4 = reinterpret_cast<const float4*>(Wq)[h];
        const float4 wk4 = reinterpret_cast<const float4*>(Wk)[h];
        const float a0  = wq4.x*wk4.x + wq4.y*wk4.y;
        const float be0 = wq4.x*wk4.y - wq4.y*wk4.x;
        const float a1  = wq4.z*wk4.z + wq4.w*wk4.w;
        const float be1 = wq4.z*wk4.w - wq4.w*wk4.z;
        const float gam = 0.5f * 1.4426950408889634f;   // 1/sqrt(QK) * log2(e)
        const float th1 = 0.031622776601683794f;

        f32x2 A[2], Bc[2], Cc[2], Dc[2], S[2], X[2];
        float vr[2];
        #pragma unroll
        for (int rr = 0; rr < 2; ++rr) {
            const int r = rr ? rB : rA;
            const float xr = x[seq * PL + r];
            const float tr = t[seq * PL + r];
            vr[rr] = mask[seq * PL + r] ? 1.f : 0.f;
            const float xc0 = xr * __cosf(tr),       xs0 = xr * __sinf(tr);
            const float xc1 = xr * __cosf(tr * th1), xs1 = xr * __sinf(tr * th1);
            A[rr]  = sp(gam * (xc0 * a0 + xs0 * be0));
            Bc[rr] = sp(gam * (xs0 * a0 - xc0 * be0));
            Cc[rr] = sp(gam * (xc1 * a1 + xs1 * be1));
            Dc[rr] = sp(gam * (xs1 * a1 - xc1 * be1));
            S[rr]  = sp(0.f);
            X[rr]  = sp(0.f);
        }

        const float* rec = tab + (size_t)seq * 768;   // uniform address -> s_load
        #pragma unroll 4
        for (int jj = 0; jj < 64; ++jj) {
            const float* p = rec + jj * 12;
            f32x2 c0p; c0p.x = p[0];  c0p.y = p[1];
            f32x2 s0p; s0p.x = p[2];  s0p.y = p[3];
            f32x2 c1p; c1p.x = p[4];  c1p.y = p[5];
            f32x2 s1p; s1p.x = p[6];  s1p.y = p[7];
            f32x2 vv;  vv.x  = p[8];  vv.y  = p[9];
            f32x2 vx;  vx.x  = p[10]; vx.y  = p[11];
            #pragma unroll
            for (int rr = 0; rr < 2; ++rr) {
                f32x2 L = A[rr] * c0p;
                L = pk_fma(Bc[rr], s0p, L);
                L = pk_fma(Cc[rr], c1p, L);
                L = pk_fma(Dc[rr], s1p, L);
                f32x2 E;
                E.x = fast_exp2(L.x);
                E.y = fast_exp2(L.y);
                S[rr] = pk_fma(E, vv, S[rr]);
                X[rr] = pk_fma(E, vx, X[rr]);
            }
        }
        const float sumx = xsum[seq];
        #pragma unroll
        for (int rr = 0; rr < 2; ++rr) {
            const int r = rr ? rB : rA;
            const float s  = S[rr].x + S[rr].y;
            const float wx = X[rr].x + X[rr].y;
            const bool  m  = vr[rr] != 0.f;
            // masked query row: uniform softmax over ALL j -> o_scal = sumx/128
            OST[h][r] = (m ? wx : sumx) / (m ? s : 128.f);
        }
    }
    __syncthreads();

    // ---- FFN: o = wv (x) o_scal; out = o.wout + bb + sum cg*relu(o.W1+b1) ----
    {
        const int qi = tid & 127, half = tid >> 7;
        const float os0 = OST[0][qi], os1 = OST[1][qi], os2 = OST[2][qi], os3 = OST[3][qi];
        const float4 wv0 = reinterpret_cast<const float4*>(Wv)[0];
        const float4 wv1 = reinterpret_cast<const float4*>(Wv)[1];
        const float4 wv2 = reinterpret_cast<const float4*>(Wv)[2];
        const float4 wv3 = reinterpret_cast<const float4*>(Wv)[3];
        float o[16];
        o[ 0] = wv0.x*os0; o[ 1] = wv0.y*os0; o[ 2] = wv0.z*os0; o[ 3] = wv0.w*os0;
        o[ 4] = wv1.x*os1; o[ 5] = wv1.y*os1; o[ 6] = wv1.z*os1; o[ 7] = wv1.w*os1;
        o[ 8] = wv2.x*os2; o[ 9] = wv2.y*os2; o[10] = wv2.z*os2; o[11] = wv2.w*os2;
        o[12] = wv3.x*os3; o[13] = wv3.y*os3; o[14] = wv3.z*os3; o[15] = wv3.w*os3;

        const f32x2* b1pair = reinterpret_cast<const f32x2*>(b1s);
        const f32x2* cgpair = reinterpret_cast<const f32x2*>(cg);
        f32x2 R2 = sp(0.f);
        const int p0 = half * 16;
        #pragma unroll 4
        for (int pp = 0; pp < 16; ++pp) {
            const int p = p0 + pp;
            f32x2 HS = b1pair[p];
            #pragma unroll
            for (int d = 0; d < 16; ++d) HS = pk_fma(w1p[p][d], sp(o[d]), HS);
            HS.x = fmaxf(HS.x, 0.f);
            HS.y = fmaxf(HS.y, 0.f);
            R2 = pk_fma(cgpair[p], HS, R2);
        }
        float r = R2.x + R2.y;
        if (half == 0) {
            float r2 = bbS;
            #pragma unroll
            for (int d = 0; d < 16; ++d) r2 += o[d] * woutS[d];
            r += r2;
        }
        P[half][qi] = r;
    }
    __syncthreads();
    if (tid < PL) out[seq * PL + tid] = P[0][tid] + P[1][tid];
}

extern "C" void kernel_launch(void* const* d_in, const int* in_sizes, int n_in,
                              void* d_out, int out_size, void* d_ws, size_t ws_size,
                              hipStream_t stream) {
    const float* x    = (const float*)d_in[0];
    const float* t    = (const float*)d_in[1];
    const int*   mask = (const int*)d_in[2];
    const float* Wq   = (const float*)d_in[3];
    const float* Wk   = (const float*)d_in[4];
    const float* Wv   = (const float*)d_in[5];
    const float* Wout = (const float*)d_in[6];
    const float* W1   = (const float*)d_in[7];
    const float* b1   = (const float*)d_in[8];
    const float* W2   = (const float*)d_in[9];
    const float* b2   = (const float*)d_in[10];
    float* outp = (float*)d_out;
    const int B = in_sizes[0] / PL;     // 2048 sequences
    float* tab  = (float*)d_ws;                       // B*768 floats (6.3 MB)
    float* xsum = tab + (size_t)B * 768;              // B floats
    stage_kernel<<<B / 4, 256, 0, stream>>>(x, t, mask, tab, xsum);
    attn_kernel<<<B, 256, 0, stream>>>(x, t, mask, tab, xsum,
                                       Wq, Wk, Wv, Wout, W1, b1, W2, b2, outp);
}

// Round 14
// 40.833 us; speedup vs baseline: 1.0720x; 1.0720x over previous
//
#include <hip/hip_runtime.h>

constexpr int PL = 128;

typedef float f32x2 __attribute__((ext_vector_type(2)));

__device__ __forceinline__ float fast_exp2(float x) {
#if __has_builtin(__builtin_amdgcn_exp2f)
    return __builtin_amdgcn_exp2f(x);
#else
    return __expf(x * 0.69314718055994531f);   // e^(x ln2) = 2^x
#endif
}
// exact IEEE f32 fma per lane; builtin codegen beat hand asm (r11 A/B)
__device__ __forceinline__ f32x2 pk_fma(f32x2 a, f32x2 b, f32x2 c) {
    return __builtin_elementwise_fma(a, b, c);
}
__device__ __forceinline__ f32x2 sp(float v) { f32x2 r; r.x = v; r.y = v; return r; }

__global__ __launch_bounds__(256, 4) void fused_block_kernel(
    const float* __restrict__ x, const float* __restrict__ t, const int* __restrict__ mask,
    const float* __restrict__ Wq, const float* __restrict__ Wk, const float* __restrict__ Wv,
    const float* __restrict__ Wout, const float* __restrict__ W1, const float* __restrict__ b1,
    const float* __restrict__ W2, const float* __restrict__ b2,
    float* __restrict__ out)
{
    // Two sequences per block. Head-independent per-position data, j-pair SoA:
    // CSM[s][jp*3+0] = {x*c0(2j), x*c0(2j+1), x*s0, x*s0'}
    // CSM[s][jp*3+1] = {x*c1, x*c1', x*s1, x*s1'}
    // CSM[s][jp*3+2] = {valid, valid', valid*x, (valid*x)'}
    __shared__ float4 CSM[2][64 * 3];
    __shared__ f32x2  w1p[32][16];      // [hid-pair][dim]
    __shared__ __align__(8) float cg[64];
    __shared__ __align__(8) float b1s[64];
    __shared__ float2 SXs[2][2][512];   // [seq][jhalf][row] = partial (S, X); 16 KB
    __shared__ float  xpart[2][2];
    __shared__ __align__(16) float woutS[16];
    __shared__ float  bbS;

    const int tid = threadIdx.x;
    const int blk = blockIdx.x;         // sequences 2*blk, 2*blk+1

    // ---- Phase 1: trig staging (thread -> (seq, position)) ----
    {
        const int seq = tid >> 7;
        const int j   = tid & 127;
        const int gb  = blk * 2 + seq;
        const int jp  = j >> 1, p = j & 1;
        const float xv = x[gb * PL + j];
        const float tv = t[gb * PL + j];
        const int   mv = mask[gb * PL + j];
        const float va = mv ? 1.0f : 0.0f;
        const float th1 = 0.031622776601683794f;   // 1000^-0.5
        const float c0 = __cosf(tv),       s0 = __sinf(tv);
        const float c1 = __cosf(tv * th1), s1 = __sinf(tv * th1);
        float* CSMf = reinterpret_cast<float*>(CSM[seq]);
        CSMf[jp*12 + 0 + p] = xv * c0;
        CSMf[jp*12 + 2 + p] = xv * s0;
        CSMf[jp*12 + 4 + p] = xv * c1;
        CSMf[jp*12 + 6 + p] = xv * s1;
        CSMf[jp*12 + 8 + p] = va;
        CSMf[jp*12 +10 + p] = va * xv;
        float px = xv;
        #pragma unroll
        for (int off = 32; off >= 1; off >>= 1) px += __shfl_xor(px, off);
        if ((tid & 63) == 0) xpart[seq][(tid >> 6) & 1] = px;
    }
    // ---- weight staging ----
    #pragma unroll
    for (int k = 0; k < 4; ++k) {
        const int idx = tid + k * 256;
        const int hid = idx >> 4, d = idx & 15;
        reinterpret_cast<float*>(w1p)[((hid >> 1) * 16 + d) * 2 + (hid & 1)] = W1[idx];
    }
    if (tid < 64) {
        b1s[tid] = b1[tid];
        float c = 0.f;
        #pragma unroll
        for (int d = 0; d < 16; ++d) c += W2[d * 64 + tid] * Wout[d];   // W2^T @ wout
        cg[tid] = c;
    }
    if (tid < 16) woutS[tid] = Wout[tid];
    if (tid == 0) {
        float bb = 0.f;
        #pragma unroll
        for (int d = 0; d < 16; ++d) bb += b2[d] * Wout[d];
        bbS = bb;
    }
    __syncthreads();

    // ---- Phase 2: j-split attention. wave = (seq, jhalf); 8 rows/lane over all
    //      4 heads; each wave reads only its 32 j-pair records (no duplicate reads). ----
    {
        const int wave = tid >> 6;
        const int seq  = wave >> 1;
        const int jh   = wave & 1;
        const int l    = tid & 63;
        const float gam = 0.5f * 1.4426950408889634f;   // 1/sqrt(QK) * log2(e)

        const float* CSMf = reinterpret_cast<const float*>(CSM[seq]);
        float xc0[2], xs0[2], xc1[2], xs1[2];
        #pragma unroll
        for (int rr = 0; rr < 2; ++rr) {                 // this lane's 2 base rows
            const int r = l + rr * 64;
            const int base = (r >> 1) * 12 + (r & 1);
            xc0[rr] = CSMf[base + 0]; xs0[rr] = CSMf[base + 2];
            xc1[rr] = CSMf[base + 4]; xs1[rr] = CSMf[base + 6];
        }
        f32x2 A[8], Bc[8], Cc[8], Dc[8], S[8], X[8];     // k = h*2+rr
        #pragma unroll
        for (int h = 0; h < 4; ++h) {
            const float4 wq4 = reinterpret_cast<const float4*>(Wq)[h];
            const float4 wk4 = reinterpret_cast<const float4*>(Wk)[h];
            const float a0  = wq4.x*wk4.x + wq4.y*wk4.y;
            const float be0 = wq4.x*wk4.y - wq4.y*wk4.x;
            const float a1  = wq4.z*wk4.z + wq4.w*wk4.w;
            const float be1 = wq4.z*wk4.w - wq4.w*wk4.z;
            #pragma unroll
            for (int rr = 0; rr < 2; ++rr) {
                const int k = h * 2 + rr;
                A[k]  = sp(gam * (xc0[rr] * a0 + xs0[rr] * be0));
                Bc[k] = sp(gam * (xs0[rr] * a0 - xc0[rr] * be0));
                Cc[k] = sp(gam * (xc1[rr] * a1 + xs1[rr] * be1));
                Dc[k] = sp(gam * (xs1[rr] * a1 - xc1[rr] * be1));
                S[k] = sp(0.f); X[k] = sp(0.f);
            }
        }
        const int j0 = jh * 32;
        #pragma unroll 2
        for (int jj = 0; jj < 32; ++jj) {
            const float4 ca = CSM[seq][(j0 + jj) * 3 + 0];   // broadcast b128
            const float4 cb = CSM[seq][(j0 + jj) * 3 + 1];
            const float4 mm = CSM[seq][(j0 + jj) * 3 + 2];
            f32x2 c0p; c0p.x = ca.x; c0p.y = ca.y;
            f32x2 s0p; s0p.x = ca.z; s0p.y = ca.w;
            f32x2 c1p; c1p.x = cb.x; c1p.y = cb.y;
            f32x2 s1p; s1p.x = cb.z; s1p.y = cb.w;
            f32x2 vv;  vv.x  = mm.x; vv.y  = mm.y;
            f32x2 vx;  vx.x  = mm.z; vx.y  = mm.w;
            #pragma unroll
            for (int k = 0; k < 8; ++k) {                // 8 independent chains
                f32x2 L = A[k] * c0p;
                L = pk_fma(Bc[k], s0p, L);
                L = pk_fma(Cc[k], c1p, L);
                L = pk_fma(Dc[k], s1p, L);
                f32x2 E;
                E.x = fast_exp2(L.x);
                E.y = fast_exp2(L.y);
                S[k] = pk_fma(E, vv, S[k]);
                X[k] = pk_fma(E, vx, X[k]);
            }
        }
        #pragma unroll
        for (int k = 0; k < 8; ++k) {
            const int row = (k >> 1) * 128 + (k & 1) * 64 + l;
            SXs[seq][jh][row] = make_float2(S[k].x + S[k].y, X[k].x + X[k].y);
        }
    }
    __syncthreads();

    // ---- Phase 3: combine j-halves; o = wv (x) o_scal; FFN + residual + out-proj ----
    {
        const int seq = tid >> 7;
        const int qi  = tid & 127;
        const float* CSMf = reinterpret_cast<const float*>(CSM[seq]);
        const float vmask = CSMf[(qi >> 1) * 12 + 8 + (qi & 1)];
        const float sumx  = xpart[seq][0] + xpart[seq][1];
        float os[4];
        #pragma unroll
        for (int h = 0; h < 4; ++h) {
            const float2 p0 = SXs[seq][0][h * 128 + qi];
            const float2 p1 = SXs[seq][1][h * 128 + qi];
            const float s  = p0.x + p1.x;
            const float wx = p0.y + p1.y;
            // masked query row: uniform softmax over ALL j -> o_scal = sumx/128
            os[h] = (vmask != 0.f) ? (wx / s) : (sumx * (1.0f / 128.0f));
        }
        const float4 wv0 = reinterpret_cast<const float4*>(Wv)[0];
        const float4 wv1 = reinterpret_cast<const float4*>(Wv)[1];
        const float4 wv2 = reinterpret_cast<const float4*>(Wv)[2];
        const float4 wv3 = reinterpret_cast<const float4*>(Wv)[3];
        float o[16];
        o[ 0] = wv0.x*os[0]; o[ 1] = wv0.y*os[0]; o[ 2] = wv0.z*os[0]; o[ 3] = wv0.w*os[0];
        o[ 4] = wv1.x*os[1]; o[ 5] = wv1.y*os[1]; o[ 6] = wv1.z*os[1]; o[ 7] = wv1.w*os[1];
        o[ 8] = wv2.x*os[2]; o[ 9] = wv2.y*os[2]; o[10] = wv2.z*os[2]; o[11] = wv2.w*os[2];
        o[12] = wv3.x*os[3]; o[13] = wv3.y*os[3]; o[14] = wv3.z*os[3]; o[15] = wv3.w*os[3];

        const f32x2* b1pair = reinterpret_cast<const f32x2*>(b1s);
        const f32x2* cgpair = reinterpret_cast<const f32x2*>(cg);
        f32x2 R2 = sp(0.f);
        #pragma unroll 4
        for (int p = 0; p < 32; ++p) {
            f32x2 HS = b1pair[p];
            #pragma unroll
            for (int d = 0; d < 16; ++d) HS = pk_fma(w1p[p][d], sp(o[d]), HS);
            HS.x = fmaxf(HS.x, 0.f);
            HS.y = fmaxf(HS.y, 0.f);
            R2 = pk_fma(cgpair[p], HS, R2);
        }
        float r = R2.x + R2.y + bbS;
        #pragma unroll
        for (int d = 0; d < 16; ++d) r += o[d] * woutS[d];
        out[(blk * 2 + seq) * PL + qi] = r;
    }
}

extern "C" void kernel_launch(void* const* d_in, const int* in_sizes, int n_in,
                              void* d_out, int out_size, void* d_ws, size_t ws_size,
                              hipStream_t stream) {
    const float* x    = (const float*)d_in[0];
    const float* t    = (const float*)d_in[1];
    const int*   mask = (const int*)d_in[2];
    const float* Wq   = (const float*)d_in[3];
    const float* Wk   = (const float*)d_in[4];
    const float* Wv   = (const float*)d_in[5];
    const float* Wout = (const float*)d_in[6];
    const float* W1   = (const float*)d_in[7];
    const float* b1   = (const float*)d_in[8];
    const float* W2   = (const float*)d_in[9];
    const float* b2   = (const float*)d_in[10];
    float* outp = (float*)d_out;
    const int B  = in_sizes[0] / PL;    // 2048 sequences
    const int B2 = B / 2;               // 2 sequences per block
    fused_block_kernel<<<B2, 256, 0, stream>>>(x, t, mask, Wq, Wk, Wv, Wout, W1, b1, W2, b2, outp);
}

// Round 15
// 27.144 us; speedup vs baseline: 1.6127x; 1.5043x over previous
//
#include <hip/hip_runtime.h>

constexpr int PL = 128;

typedef float f32x2 __attribute__((ext_vector_type(2)));

__device__ __forceinline__ float fast_exp2(float x) {
#if __has_builtin(__builtin_amdgcn_exp2f)
    return __builtin_amdgcn_exp2f(x);
#else
    return __expf(x * 0.69314718055994531f);   // e^(x ln2) = 2^x
#endif
}
// exact IEEE f32 fma per lane; builtin codegen beat hand asm (r11 A/B)
__device__ __forceinline__ f32x2 pk_fma(f32x2 a, f32x2 b, f32x2 c) {
    return __builtin_elementwise_fma(a, b, c);
}
__device__ __forceinline__ f32x2 sp(float v) { f32x2 r; r.x = v; r.y = v; return r; }

__global__ __launch_bounds__(256, 4) void fused_block_kernel(
    const float* __restrict__ x, const float* __restrict__ t, const int* __restrict__ mask,
    const float* __restrict__ Wq, const float* __restrict__ Wk, const float* __restrict__ Wv,
    const float* __restrict__ Wout, const float* __restrict__ W1, const float* __restrict__ b1,
    const float* __restrict__ W2, const float* __restrict__ b2,
    float* __restrict__ out)
{
    // Two sequences per block. j-records COMPACTED to valid-only positions:
    // CSMc[s][p*3+0] = {x*c0(a), x*c0(b), x*s0(a), x*s0(b)}   (a,b = compacted pair)
    // CSMc[s][p*3+1] = {x*c1, x*c1', x*s1, x*s1'}
    // CSMc[s][p*3+2] = {1, 1, x, x'}          (pad slot: all zeros -> contributes 0)
    __shared__ float4 CSMc[2][64 * 3];
    __shared__ float4 ROWD[2][PL];      // per-row {x*c0, x*s0, x*c1, x*s1}
    __shared__ float  validR[2][PL];
    __shared__ f32x2  w1p[32][16];      // [hid-pair][dim]
    __shared__ __align__(8) float cg[64];
    __shared__ __align__(8) float b1s[64];
    __shared__ float  OST[2][4][PL];
    __shared__ float  xpart[2][2];
    __shared__ int    wcnt[2][2];       // valid count per (seq, wave-half)
    __shared__ __align__(16) float woutS[16];
    __shared__ float  bbS;

    const int tid  = threadIdx.x;
    const int blk  = blockIdx.x;        // sequences 2*blk, 2*blk+1
    const int seq  = tid >> 7;
    const int j    = tid & 127;
    const int lane = tid & 63;
    const int wh   = (tid >> 6) & 1;    // wave-half within seq (j<64 / j>=64)

    // ---- Phase 1: per-position trig + row data + valid ballot ----
    const float xv = x[(blk * 2 + seq) * PL + j];
    const float tv = t[(blk * 2 + seq) * PL + j];
    const int   mv = mask[(blk * 2 + seq) * PL + j];
    const float va = mv ? 1.0f : 0.0f;
    float xc0v, xs0v, xc1v, xs1v;
    {
        const float th1 = 0.031622776601683794f;   // 1000^-0.5
        xc0v = xv * __cosf(tv);        xs0v = xv * __sinf(tv);
        xc1v = xv * __cosf(tv * th1);  xs1v = xv * __sinf(tv * th1);
        ROWD[seq][j]   = make_float4(xc0v, xs0v, xc1v, xs1v);
        validR[seq][j] = va;
        float px = xv;
        #pragma unroll
        for (int off = 32; off >= 1; off >>= 1) px += __shfl_xor(px, off);
        if (lane == 0) xpart[seq][wh] = px;
    }
    const unsigned long long ball = __ballot(mv != 0);
    const int lpos = __popcll(ball & ((1ull << lane) - 1ull));
    if (lane == 0) wcnt[seq][wh] = __popcll(ball);

    // ---- weight staging ----
    #pragma unroll
    for (int k = 0; k < 4; ++k) {
        const int idx = tid + k * 256;
        const int hid = idx >> 4, d = idx & 15;
        reinterpret_cast<float*>(w1p)[((hid >> 1) * 16 + d) * 2 + (hid & 1)] = W1[idx];
    }
    if (tid < 64) {
        b1s[tid] = b1[tid];
        float c = 0.f;
        #pragma unroll
        for (int d = 0; d < 16; ++d) c += W2[d * 64 + tid] * Wout[d];   // W2^T @ wout
        cg[tid] = c;
    }
    if (tid < 16) woutS[tid] = Wout[tid];
    if (tid == 0) {
        float bb = 0.f;
        #pragma unroll
        for (int d = 0; d < 16; ++d) bb += b2[d] * Wout[d];
        bbS = bb;
    }
    __syncthreads();

    // ---- Phase 1b: scatter valid j-records into compacted slots ----
    {
        float* C = reinterpret_cast<float*>(CSMc[seq]);
        const int pos = lpos + (wh ? wcnt[seq][0] : 0);
        if (mv) {
            const int p = pos >> 1, par = pos & 1;
            C[p*12 + 0 + par] = xc0v;
            C[p*12 + 2 + par] = xs0v;
            C[p*12 + 4 + par] = xc1v;
            C[p*12 + 6 + par] = xs1v;
            C[p*12 + 8 + par] = 1.0f;
            C[p*12 +10 + par] = xv;
        }
        const int nv = wcnt[seq][0] + wcnt[seq][1];
        if (j == 0 && (nv & 1)) {       // zero the odd-tail pad slot (vv=0 -> no contribution)
            const int p = nv >> 1;
            C[p*12 + 1] = 0.f; C[p*12 + 3] = 0.f; C[p*12 + 5] = 0.f;
            C[p*12 + 7] = 0.f; C[p*12 + 9] = 0.f; C[p*12 +11] = 0.f;
        }
    }
    __syncthreads();

    // ---- Phase 2: attention over compacted (valid-only) keys; 4 rows/lane ----
    {
        const int wave = tid >> 6;
        const int sq   = wave >> 1;
        const int hh   = wave & 1;
        const int l2   = tid & 63;
        const int h    = hh * 2 + (l2 >> 5);     // 2 heads per wave
        const int r0   = l2 & 31;                // rows r0 + 32*rr
        const float4 wq4 = reinterpret_cast<const float4*>(Wq)[h];
        const float4 wk4 = reinterpret_cast<const float4*>(Wk)[h];
        const float a0  = wq4.x*wk4.x + wq4.y*wk4.y;
        const float be0 = wq4.x*wk4.y - wq4.y*wk4.x;
        const float a1  = wq4.z*wk4.z + wq4.w*wk4.w;
        const float be1 = wq4.z*wk4.w - wq4.w*wk4.z;
        const float gam = 0.5f * 1.4426950408889634f;   // 1/sqrt(QK) * log2(e)

        float vr[4];
        f32x2 A[4], Bc[4], Cc[4], Dc[4], S[4], X[4];
        #pragma unroll
        for (int rr = 0; rr < 4; ++rr) {
            const int r = r0 + rr * 32;
            const float4 rd = ROWD[sq][r];
            vr[rr] = validR[sq][r];
            A[rr]  = sp(gam * (rd.x * a0 + rd.y * be0));
            Bc[rr] = sp(gam * (rd.y * a0 - rd.x * be0));
            Cc[rr] = sp(gam * (rd.z * a1 + rd.w * be1));
            Dc[rr] = sp(gam * (rd.w * a1 - rd.z * be1));
            S[rr] = sp(0.f);
            X[rr] = sp(0.f);
        }
        const int nv    = wcnt[sq][0] + wcnt[sq][1];
        const int npair = (nv + 1) >> 1;
        #pragma unroll 2
        for (int jj = 0; jj < npair; ++jj) {
            const float4 ca = CSMc[sq][jj * 3 + 0];   // wave-uniform broadcast b128
            const float4 cb = CSMc[sq][jj * 3 + 1];
            const float4 mm = CSMc[sq][jj * 3 + 2];
            f32x2 c0p; c0p.x = ca.x; c0p.y = ca.y;
            f32x2 s0p; s0p.x = ca.z; s0p.y = ca.w;
            f32x2 c1p; c1p.x = cb.x; c1p.y = cb.y;
            f32x2 s1p; s1p.x = cb.z; s1p.y = cb.w;
            f32x2 vv;  vv.x  = mm.x; vv.y  = mm.y;
            f32x2 vx;  vx.x  = mm.z; vx.y  = mm.w;
            #pragma unroll
            for (int rr = 0; rr < 4; ++rr) {
                f32x2 L = A[rr] * c0p;
                L = pk_fma(Bc[rr], s0p, L);
                L = pk_fma(Cc[rr], c1p, L);
                L = pk_fma(Dc[rr], s1p, L);
                f32x2 E;
                E.x = fast_exp2(L.x);
                E.y = fast_exp2(L.y);
                S[rr] = pk_fma(E, vv, S[rr]);
                X[rr] = pk_fma(E, vx, X[rr]);
            }
        }
        const float sumx = xpart[sq][0] + xpart[sq][1];
        #pragma unroll
        for (int rr = 0; rr < 4; ++rr) {
            const int r = r0 + rr * 32;
            const float s  = S[rr].x + S[rr].y;
            const float wx = X[rr].x + X[rr].y;
            const bool  m  = vr[rr] != 0.f;
            // masked query row: uniform softmax over ALL j -> o_scal = sumx/128
            OST[sq][h][r] = (m ? wx : sumx) / (m ? s : 128.f);
        }
    }
    __syncthreads();

    // ---- Phase 3: o = wv (x) o_scal; out = o.wout + bb + sum cg*relu(o.W1+b1) ----
    {
        const int qi = j;
        const float vmask = validR[seq][qi];
        (void)vmask;
        const float os0 = OST[seq][0][qi], os1 = OST[seq][1][qi];
        const float os2 = OST[seq][2][qi], os3 = OST[seq][3][qi];
        const float4 wv0 = reinterpret_cast<const float4*>(Wv)[0];
        const float4 wv1 = reinterpret_cast<const float4*>(Wv)[1];
        const float4 wv2 = reinterpret_cast<const float4*>(Wv)[2];
        const float4 wv3 = reinterpret_cast<const float4*>(Wv)[3];
        float o[16];
        o[ 0] = wv0.x*os0; o[ 1] = wv0.y*os0; o[ 2] = wv0.z*os0; o[ 3] = wv0.w*os0;
        o[ 4] = wv1.x*os1; o[ 5] = wv1.y*os1; o[ 6] = wv1.z*os1; o[ 7] = wv1.w*os1;
        o[ 8] = wv2.x*os2; o[ 9] = wv2.y*os2; o[10] = wv2.z*os2; o[11] = wv2.w*os2;
        o[12] = wv3.x*os3; o[13] = wv3.y*os3; o[14] = wv3.z*os3; o[15] = wv3.w*os3;

        const f32x2* b1pair = reinterpret_cast<const f32x2*>(b1s);
        const f32x2* cgpair = reinterpret_cast<const f32x2*>(cg);
        f32x2 R2 = sp(0.f);
        #pragma unroll 4
        for (int p = 0; p < 32; ++p) {
            f32x2 HS = b1pair[p];
            #pragma unroll
            for (int d = 0; d < 16; ++d) HS = pk_fma(w1p[p][d], sp(o[d]), HS);
            HS.x = fmaxf(HS.x, 0.f);
            HS.y = fmaxf(HS.y, 0.f);
            R2 = pk_fma(cgpair[p], HS, R2);
        }
        float r = R2.x + R2.y + bbS;
        #pragma unroll
        for (int d = 0; d < 16; ++d) r += o[d] * woutS[d];
        out[(blk * 2 + seq) * PL + qi] = r;
    }
}

extern "C" void kernel_launch(void* const* d_in, const int* in_sizes, int n_in,
                              void* d_out, int out_size, void* d_ws, size_t ws_size,
                              hipStream_t stream) {
    const float* x    = (const float*)d_in[0];
    const float* t    = (const float*)d_in[1];
    const int*   mask = (const int*)d_in[2];
    const float* Wq   = (const float*)d_in[3];
    const float* Wk   = (const float*)d_in[4];
    const float* Wv   = (const float*)d_in[5];
    const float* Wout = (const float*)d_in[6];
    const float* W1   = (const float*)d_in[7];
    const float* b1   = (const float*)d_in[8];
    const float* W2   = (const float*)d_in[9];
    const float* b2   = (const float*)d_in[10];
    float* outp = (float*)d_out;
    const int B  = in_sizes[0] / PL;    // 2048 sequences
    const int B2 = B / 2;               // 2 sequences per block
    fused_block_kernel<<<B2, 256, 0, stream>>>(x, t, mask, Wq, Wk, Wv, Wout, W1, b1, W2, b2, outp);
}